// Round 6
// baseline (466.428 us; speedup 1.0000x reference)
//
#include <hip/hip_runtime.h>
#include <stdint.h>
#include <stddef.h>

typedef __bf16 bf16_t;
typedef __bf16 bf16x8 __attribute__((ext_vector_type(8)));
typedef __bf16 bf16x4 __attribute__((ext_vector_type(4)));
typedef __bf16 bf16x2 __attribute__((ext_vector_type(2)));
typedef float  f32x4  __attribute__((ext_vector_type(4)));

#define SEQ   3072
#define DIMD  2048
#define NH    16
#define HD    128
#define QKVN  6144

__device__ __forceinline__ void async16(const bf16_t* g, bf16_t* l) {
  __builtin_amdgcn_global_load_lds((const __attribute__((address_space(1))) uint32_t*)g,
                                   (__attribute__((address_space(3))) uint32_t*)l, 16, 0, 0);
}

// ---------------- fused converts + bias pack (one launch) ----------------
__global__ __launch_bounds__(256) void cvt_all(const float* __restrict__ x,
                                               const float* __restrict__ Wq,
                                               const float* __restrict__ Wk,
                                               const float* __restrict__ Wv,
                                               const float* __restrict__ Wo,
                                               const float* __restrict__ bq,
                                               const float* __restrict__ bk,
                                               const float* __restrict__ bv,
                                               bf16_t* __restrict__ xb,
                                               bf16_t* __restrict__ Wqkvb,
                                               bf16_t* __restrict__ Wob,
                                               float* __restrict__ bqkv) {
  const int b = blockIdx.x;
  const float* src; bf16_t* dst; int off;
  if (b < 3072)       { src = x;  dst = xb;              off = b; }
  else if (b < 5120)  { src = Wq; dst = Wqkvb;           off = b - 3072; }
  else if (b < 7168)  { src = Wk; dst = Wqkvb + 4194304; off = b - 5120; }
  else if (b < 9216)  { src = Wv; dst = Wqkvb + 8388608; off = b - 7168; }
  else if (b < 11264) { src = Wo; dst = Wob;             off = b - 9216; }
  else {  // bias pack: 24 blocks cover 6144
    int t = (b - 11264) * 256 + threadIdx.x;
    float v;
    if (t < 2048)      v = bq[t];
    else if (t < 4096) v = bk[t - 2048];
    else               v = bv[t - 4096];
    bqkv[t] = v;
    return;
  }
  const int idx = (off * 256 + threadIdx.x) * 8;
  const float4 a = *(const float4*)(src + idx);
  const float4 c = *(const float4*)(src + idx + 4);
  bf16x8 o;
  o[0] = (bf16_t)a.x; o[1] = (bf16_t)a.y; o[2] = (bf16_t)a.z; o[3] = (bf16_t)a.w;
  o[4] = (bf16_t)c.x; o[5] = (bf16_t)c.y; o[6] = (bf16_t)c.z; o[7] = (bf16_t)c.w;
  *(bf16x8*)(dst + idx) = o;
}

// ---------------- GEMM: C[M,N] = A[M,K] * B[N,K]^T + bias ----------------
template<bool OUT_BF16>
__global__ __launch_bounds__(256, 2) void gemm_nt(const bf16_t* __restrict__ A,
                                                  const bf16_t* __restrict__ B,
                                                  const float* __restrict__ bias,
                                                  void* __restrict__ Cout,
                                                  int M, int N, int K) {
  __shared__ __align__(16) bf16_t As[128 * 64];
  __shared__ __align__(16) bf16_t Bs[128 * 64];
  const int t = threadIdx.x;
  const int lane = t & 63, wave = t >> 6;
  const int quad = lane >> 4, l15 = lane & 15;
  const int wy = wave >> 1, wx = wave & 1;
  const size_t bm = (size_t)blockIdx.y * 128, bn = (size_t)blockIdx.x * 128;
  const bf16_t* Ab = A + bm * K;
  const bf16_t* Bb = B + bn * K;
  f32x4 acc[4][4] = {};
  int srow[4], scol[4];
#pragma unroll
  for (int r = 0; r < 4; r++) {
    int L = r * 256 + t;
    int row = L >> 3, cp = L & 7;
    srow[r] = row;
    scol[r] = (cp ^ (row & 7)) * 8;
  }
  for (int k0 = 0; k0 < K; k0 += 64) {
    __syncthreads();
#pragma unroll
    for (int r = 0; r < 4; r++)
      async16(Ab + (size_t)srow[r] * K + k0 + scol[r], &As[(r * 256 + t) * 8]);
#pragma unroll
    for (int r = 0; r < 4; r++)
      async16(Bb + (size_t)srow[r] * K + k0 + scol[r], &Bs[(r * 256 + t) * 8]);
    __syncthreads();
#pragma unroll
    for (int ks = 0; ks < 2; ks++) {
      bf16x8 af[4], bfv[4];
#pragma unroll
      for (int i = 0; i < 4; i++) {
        int row = wy * 64 + i * 16 + l15;
        af[i] = *(const bf16x8*)&As[row * 64 + (((ks * 4 + quad) ^ (row & 7)) * 8)];
      }
#pragma unroll
      for (int j = 0; j < 4; j++) {
        int row = wx * 64 + j * 16 + l15;
        bfv[j] = *(const bf16x8*)&Bs[row * 64 + (((ks * 4 + quad) ^ (row & 7)) * 8)];
      }
#pragma unroll
      for (int i = 0; i < 4; i++)
#pragma unroll
        for (int j = 0; j < 4; j++)
          acc[i][j] = __builtin_amdgcn_mfma_f32_16x16x32_bf16(af[i], bfv[j], acc[i][j], 0, 0, 0);
    }
  }
#pragma unroll
  for (int i = 0; i < 4; i++) {
#pragma unroll
    for (int j = 0; j < 4; j++) {
      size_t row = bm + wy * 64 + i * 16 + quad * 4;
      size_t col = bn + wx * 64 + j * 16 + l15;
      float bb = bias[col];
#pragma unroll
      for (int r = 0; r < 4; r++) {
        float v = acc[i][j][r] + bb;
        if (OUT_BF16) ((bf16_t*)Cout)[(row + r) * N + col] = (bf16_t)v;
        else          ((float*)Cout)[(row + r) * N + col] = v;
      }
    }
  }
}

// ---------------- RMS + RoPE; q in-place, k packed to pk[h][s][d] ----------------
__global__ __launch_bounds__(256) void rmsrope(bf16_t* __restrict__ qkv,
                                               bf16_t* __restrict__ pk,
                                               const float* __restrict__ gq,
                                               const float* __restrict__ gk,
                                               const float* __restrict__ freqs) {
  const int s = blockIdx.x, t = threadIdx.x;
  bf16_t* row = qkv + (size_t)s * QKVN;
  bf16x8 qv = *(const bf16x8*)&row[t * 8];
  bf16x8 kv = *(const bf16x8*)&row[2048 + t * 8];
  float qf[8], kf[8];
  float qs = 0.f, ks2 = 0.f;
#pragma unroll
  for (int i = 0; i < 8; i++) {
    qf[i] = (float)qv[i]; qs  += qf[i] * qf[i];
    kf[i] = (float)kv[i]; ks2 += kf[i] * kf[i];
  }
#pragma unroll
  for (int m = 1; m < 64; m <<= 1) {
    qs  += __shfl_xor(qs, m);
    ks2 += __shfl_xor(ks2, m);
  }
  __shared__ float red[2][4];
  const int wave = t >> 6, lane = t & 63;
  if (lane == 0) { red[0][wave] = qs; red[1][wave] = ks2; }
  __syncthreads();
  qs  = red[0][0] + red[0][1] + red[0][2] + red[0][3];
  ks2 = red[1][0] + red[1][1] + red[1][2] + red[1][3];
  const float qsc = rsqrtf(qs  / 2048.f + 1e-6f);
  const float ksc = rsqrtf(ks2 / 2048.f + 1e-6f);
  const int sf = s / 384, rem = s - sf * 384;
  const int sh = rem / 24, sw = rem - sh * 24;
  bf16x8 qo, ko;
#pragma unroll
  for (int u = 0; u < 4; u++) {
    const int col = t * 8 + 2 * u;
    const int i = (col >> 1) & 63;                         // pair index within head (c=64)
    const int frow = (i < 22) ? sf : ((i < 43) ? sh : sw); // cf=22, ch=cw=21
    const float ang = freqs[frow * 64 + i];
    float sn, cs;
    __sincosf(ang, &sn, &cs);
    float te = qf[2 * u]     * qsc * gq[col];
    float to = qf[2 * u + 1] * qsc * gq[col + 1];
    qo[2 * u]     = (bf16_t)(te * cs - to * sn);
    qo[2 * u + 1] = (bf16_t)(te * sn + to * cs);
    te = kf[2 * u]     * ksc * gk[col];
    to = kf[2 * u + 1] * ksc * gk[col + 1];
    ko[2 * u]     = (bf16_t)(te * cs - to * sn);
    ko[2 * u + 1] = (bf16_t)(te * sn + to * cs);
  }
  *(bf16x8*)&row[t * 8] = qo;
  // packed K: pk[h][s][d], h = t>>4, d = (t&15)*8
  *(bf16x8*)&pk[((size_t)(t >> 4) * SEQ + s) * HD + (t & 15) * 8] = ko;
}

// ---------------- V transpose: pvt[h][d][s] = qkv[s][4096 + h*128 + d] ----------------
__global__ __launch_bounds__(256) void vtrans(const bf16_t* __restrict__ qkv,
                                              bf16_t* __restrict__ pvt) {
  __shared__ bf16_t tile[128][65];
  const int h = blockIdx.y;
  const int s0 = blockIdx.x * 64;
  const int t = threadIdx.x;
#pragma unroll
  for (int r = 0; r < 4; r++) {
    int L = r * 256 + t, s = L >> 4, cp = L & 15;
    bf16x8 v = *(const bf16x8*)&qkv[(size_t)(s0 + s) * QKVN + 4096 + h * HD + cp * 8];
#pragma unroll
    for (int i = 0; i < 8; i++) tile[cp * 8 + i][s] = v[i];
  }
  __syncthreads();
#pragma unroll
  for (int r = 0; r < 4; r++) {
    int L = r * 256 + t, d = L >> 3, c = L & 7;
    bf16x8 o;
#pragma unroll
    for (int i = 0; i < 8; i++) o[i] = tile[d][c * 8 + i];
    *(bf16x8*)&pvt[((size_t)h * HD + d) * SEQ + s0 + c * 8] = o;
  }
}

// ---------------- Flash attention: q-tile 192, 6 waves, 256 blocks = 1/CU ----------------
// Block = (q-tile 192, head), grid dim3(16,16) -> exactly one block per CU, uniform
// makespan. Each wave owns 32 q rows (identical structure to the proven R5 wave).
// LDS double-buffered K/V, one barrier/iter. exp2-domain softmax; ballot-skipped
// O-rescale (alpha==1 on most iterations once m_run converges).
__global__ __launch_bounds__(384, 1) void flash_attn(const bf16_t* __restrict__ qkv,
                                                     const bf16_t* __restrict__ pk,
                                                     const bf16_t* __restrict__ pvt,
                                                     bf16_t* __restrict__ ob) {
  __shared__ __align__(16) bf16_t Ks[2][64 * 128];  // [kv][d], 16 chunks/row, xor-swizzled
  __shared__ __align__(16) bf16_t Vt[2][128 * 64];  // [d][kv], 8 chunks/row, xor-swizzled
  __shared__ __align__(16) bf16_t Ps[6][32 * 64];   // per-wave P [q][kv], swizzled
  const int h = blockIdx.y, qt = blockIdx.x;
  const int s0 = qt * 192;
  const int t = threadIdx.x, wave = t >> 6, lane = t & 63;
  const int quad = lane >> 4, l15 = lane & 15;
  const int wq = wave * 32;
  // exp2 domain: fold log2(e) into the score scale
  const float scale2 = 0.08838834764831845f * 1.44269504088896f;
  const bf16_t* pkh = pk  + (size_t)h * (SEQ * HD);
  const bf16_t* pvh = pvt + (size_t)h * (HD * SEQ);
  bf16x8 qfr[2][4];
#pragma unroll
  for (int tj = 0; tj < 2; tj++)
#pragma unroll
    for (int ks = 0; ks < 4; ks++)
      qfr[tj][ks] = *(const bf16x8*)&qkv[(size_t)(s0 + wq + tj * 16 + l15) * QKVN + h * HD + ks * 32 + quad * 8];
  f32x4 oacc[2][8] = {};
  float m_run[2] = {-3e38f, -3e38f}, l_run[2] = {0.f, 0.f};
  // preload tile 0 into buffer 0 (1024 K-chunks + 1024 V-chunks over 384 threads)
  for (int L = t; L < 1024; L += 384) {
    int krow = L >> 4, c = (L & 15) ^ (krow & 7);
    async16(pkh + (size_t)krow * HD + c * 8, &Ks[0][L * 8]);
  }
  for (int L = t; L < 1024; L += 384) {
    int d = L >> 3, c = (L & 7) ^ (d & 7);
    async16(pvh + (size_t)d * SEQ + c * 8, &Vt[0][L * 8]);
  }
  for (int kt = 0; kt < SEQ / 64; kt++) {
    const int cur = kt & 1;
    __syncthreads();  // tile kt landed; all waves done reading buf cur^1
    if (kt + 1 < SEQ / 64) {
      const int kv1 = (kt + 1) * 64;
      for (int L = t; L < 1024; L += 384) {
        int krow = L >> 4, c = (L & 15) ^ (krow & 7);
        async16(pkh + (size_t)(kv1 + krow) * HD + c * 8, &Ks[cur ^ 1][L * 8]);
      }
      for (int L = t; L < 1024; L += 384) {
        int d = L >> 3, c = (L & 7) ^ (d & 7);
        async16(pvh + (size_t)d * SEQ + kv1 + c * 8, &Vt[cur ^ 1][L * 8]);
      }
    }
    // S^T = K * Q^T  -> lane holds S^T[kv=ti*16+quad*4+r][q=tj*16+l15]
    f32x4 st[4][2] = {};
#pragma unroll
    for (int ks = 0; ks < 4; ks++) {
      bf16x8 kfr[4];
#pragma unroll
      for (int ti = 0; ti < 4; ti++) {
        const int kr = ti * 16 + l15;
        kfr[ti] = *(const bf16x8*)&Ks[cur][kr * 128 + (((ks * 4 + quad) ^ (kr & 7)) * 8)];
      }
#pragma unroll
      for (int ti = 0; ti < 4; ti++)
#pragma unroll
        for (int tj = 0; tj < 2; tj++)
          st[ti][tj] = __builtin_amdgcn_mfma_f32_16x16x32_bf16(kfr[ti], qfr[tj][ks], st[ti][tj], 0, 0, 0);
    }
    // online softmax over kv (column reduction of S^T = across quads), exp2 domain
    float mt[2] = {-3e38f, -3e38f};
#pragma unroll
    for (int ti = 0; ti < 4; ti++)
#pragma unroll
      for (int tj = 0; tj < 2; tj++)
#pragma unroll
        for (int r = 0; r < 4; r++) {
          st[ti][tj][r] *= scale2;
          mt[tj] = fmaxf(mt[tj], st[ti][tj][r]);
        }
    float al[2];
#pragma unroll
    for (int tj = 0; tj < 2; tj++) {
      mt[tj] = fmaxf(mt[tj], __shfl_xor(mt[tj], 16));
      mt[tj] = fmaxf(mt[tj], __shfl_xor(mt[tj], 32));
      const float mn = fmaxf(m_run[tj], mt[tj]);
      al[tj] = exp2f(m_run[tj] - mn);
      m_run[tj] = mn;
    }
    float lt[2] = {0.f, 0.f};
#pragma unroll
    for (int ti = 0; ti < 4; ti++)
#pragma unroll
      for (int tj = 0; tj < 2; tj++) {
        bf16x4 pv;
#pragma unroll
        for (int r = 0; r < 4; r++) {
          const float p = exp2f(st[ti][tj][r] - m_run[tj]);
          pv[r] = (bf16_t)p;
          lt[tj] += (float)pv[r];  // denominator consistent with rounded P
        }
        const int q = tj * 16 + l15;
        const int cp2 = (ti * 2 + (quad >> 1)) ^ (q & 7);
        *(bf16x4*)&Ps[wave][q * 64 + cp2 * 8 + (quad & 1) * 4] = pv;
      }
#pragma unroll
    for (int tj = 0; tj < 2; tj++) {
      lt[tj] += __shfl_xor(lt[tj], 16);
      lt[tj] += __shfl_xor(lt[tj], 32);
      l_run[tj] = l_run[tj] * al[tj] + lt[tj];
    }
    // rescale O accumulators only when some alpha != 1 (ballot-skip)
    if (__ballot((al[0] != 1.f) | (al[1] != 1.f))) {
#pragma unroll
      for (int ti = 0; ti < 2; ti++) {
        float a0 = __shfl(al[ti], quad * 4 + 0);
        float a1 = __shfl(al[ti], quad * 4 + 1);
        float a2 = __shfl(al[ti], quad * 4 + 2);
        float a3 = __shfl(al[ti], quad * 4 + 3);
#pragma unroll
        for (int dj = 0; dj < 8; dj++) {
          oacc[ti][dj][0] *= a0; oacc[ti][dj][1] *= a1;
          oacc[ti][dj][2] *= a2; oacc[ti][dj][3] *= a3;
        }
      }
    }
    // O += P * V
#pragma unroll
    for (int ks = 0; ks < 2; ks++) {
      bf16x8 pf[2], vf[8];
#pragma unroll
      for (int ti = 0; ti < 2; ti++) {
        const int q = ti * 16 + l15;
        pf[ti] = *(const bf16x8*)&Ps[wave][q * 64 + (((ks * 4 + quad) ^ (q & 7)) * 8)];
      }
#pragma unroll
      for (int dj = 0; dj < 8; dj++) {
        const int d = dj * 16 + l15;
        vf[dj] = *(const bf16x8*)&Vt[cur][d * 64 + (((ks * 4 + quad) ^ (d & 7)) * 8)];
      }
#pragma unroll
      for (int ti = 0; ti < 2; ti++)
#pragma unroll
        for (int dj = 0; dj < 8; dj++)
          oacc[ti][dj] = __builtin_amdgcn_mfma_f32_16x16x32_bf16(pf[ti], vf[dj], oacc[ti][dj], 0, 0, 0);
    }
  }
  // epilogue: divide by l, store bf16 into ob [s][n*d]
#pragma unroll
  for (int ti = 0; ti < 2; ti++) {
    float li[4];
#pragma unroll
    for (int r = 0; r < 4; r++) li[r] = 1.f / __shfl(l_run[ti], quad * 4 + r);
#pragma unroll
    for (int dj = 0; dj < 8; dj++)
#pragma unroll
      for (int r = 0; r < 4; r++) {
        const float v = oacc[ti][dj][r] * li[r];
        ob[(size_t)(s0 + wq + ti * 16 + quad * 4 + r) * DIMD + h * HD + dj * 16 + l15] = (bf16_t)v;
      }
  }
}

// ---------------- launch ----------------
extern "C" void kernel_launch(void* const* d_in, const int* in_sizes, int n_in,
                              void* d_out, int out_size, void* d_ws, size_t ws_size,
                              hipStream_t stream) {
  (void)in_sizes; (void)n_in; (void)out_size;
  const float* x     = (const float*)d_in[0];
  const float* freqs = (const float*)d_in[1];
  const float* Wq    = (const float*)d_in[2];
  const float* bq    = (const float*)d_in[3];
  const float* Wk    = (const float*)d_in[4];
  const float* bk    = (const float*)d_in[5];
  const float* Wv    = (const float*)d_in[6];
  const float* bv    = (const float*)d_in[7];
  const float* Wo    = (const float*)d_in[8];
  const float* bo    = (const float*)d_in[9];
  const float* gq    = (const float*)d_in[10];
  const float* gk    = (const float*)d_in[11];

  // workspace carve (bytes); [0, 37748736) holds xb+Wqkvb during gemm1,
  // reused afterwards for pk / pvt.
  char* w = (char*)d_ws;
  bf16_t* xb    = (bf16_t*)(w);                 // x bf16:        12,582,912 B
  bf16_t* Wqkvb = (bf16_t*)(w + 12582912);      // Wq|Wk|Wv bf16: 25,165,824 B
  bf16_t* Wob   = (bf16_t*)(w + 37748736);      // Wo bf16:        8,388,608 B
  bf16_t* qkvb  = (bf16_t*)(w + 46137344);      // qkv bf16:      37,748,736 B
  bf16_t* obuf  = (bf16_t*)(w + 83886080);      // attn out bf16: 12,582,912 B
  float*  bqkv  = (float*) (w + 96468992);      // stacked bias:      24,576 B
  bf16_t* pk    = (bf16_t*)(w);                 // K packed [16][3072][128]: 12,582,912 B
  bf16_t* pvt   = (bf16_t*)(w + 12582912);      // V^T [16][128][3072]:      12,582,912 B
  if (ws_size < (size_t)96493568) return;

  // converts + bias pack (one launch)
  cvt_all<<<11288, 256, 0, stream>>>(x, Wq, Wk, Wv, Wo, bq, bk, bv, xb, Wqkvb, Wob, bqkv);

  // qkv = x @ [Wq;Wk;Wv]^T + bias   (3072 x 6144 x 2048)
  gemm_nt<true><<<dim3(48, 24), 256, 0, stream>>>(xb, Wqkvb, bqkv, qkvb, SEQ, QKVN, DIMD);
  // RMS(q,k) * g + grid RoPE; q in-place, k -> pk (packed per head)
  rmsrope<<<3072, 256, 0, stream>>>(qkvb, pk, gq, gk, freqs);
  // V transpose -> pvt[h][d][s]
  vtrans<<<dim3(48, NH), 256, 0, stream>>>(qkvb, pvt);
  // attention (q-tile 192, 6 waves, 1 block/CU, double-buffered) -> obuf
  flash_attn<<<dim3(16, NH), 384, 0, stream>>>(qkvb, pk, pvt, obuf);
  // out = obuf @ Wo^T + bo  (3072 x 2048 x 2048), fp32 out
  gemm_nt<false><<<dim3(16, 24), 256, 0, stream>>>(obuf, Wob, bo, (float*)d_out, SEQ, DIMD, DIMD);
}

// Round 7
// 446.068 us; speedup vs baseline: 1.0456x; 1.0456x over previous
//
#include <hip/hip_runtime.h>
#include <stdint.h>
#include <stddef.h>

typedef __bf16 bf16_t;
typedef __bf16 bf16x8 __attribute__((ext_vector_type(8)));
typedef __bf16 bf16x4 __attribute__((ext_vector_type(4)));
typedef __bf16 bf16x2 __attribute__((ext_vector_type(2)));
typedef float  f32x4  __attribute__((ext_vector_type(4)));

#define SEQ   3072
#define DIMD  2048
#define NH    16
#define HD    128
#define QKVN  6144

__device__ __forceinline__ void async16(const bf16_t* g, bf16_t* l) {
  __builtin_amdgcn_global_load_lds((const __attribute__((address_space(1))) uint32_t*)g,
                                   (__attribute__((address_space(3))) uint32_t*)l, 16, 0, 0);
}

// ---------------- fused converts + bias pack (one launch) ----------------
__global__ __launch_bounds__(256) void cvt_all(const float* __restrict__ x,
                                               const float* __restrict__ Wq,
                                               const float* __restrict__ Wk,
                                               const float* __restrict__ Wv,
                                               const float* __restrict__ Wo,
                                               const float* __restrict__ bq,
                                               const float* __restrict__ bk,
                                               const float* __restrict__ bv,
                                               bf16_t* __restrict__ xb,
                                               bf16_t* __restrict__ Wqkvb,
                                               bf16_t* __restrict__ Wob,
                                               float* __restrict__ bqkv) {
  const int b = blockIdx.x;
  const float* src; bf16_t* dst; int off;
  if (b < 3072)       { src = x;  dst = xb;              off = b; }
  else if (b < 5120)  { src = Wq; dst = Wqkvb;           off = b - 3072; }
  else if (b < 7168)  { src = Wk; dst = Wqkvb + 4194304; off = b - 5120; }
  else if (b < 9216)  { src = Wv; dst = Wqkvb + 8388608; off = b - 7168; }
  else if (b < 11264) { src = Wo; dst = Wob;             off = b - 9216; }
  else {  // bias pack: 24 blocks cover 6144
    int t = (b - 11264) * 256 + threadIdx.x;
    float v;
    if (t < 2048)      v = bq[t];
    else if (t < 4096) v = bk[t - 2048];
    else               v = bv[t - 4096];
    bqkv[t] = v;
    return;
  }
  const int idx = (off * 256 + threadIdx.x) * 8;
  const float4 a = *(const float4*)(src + idx);
  const float4 c = *(const float4*)(src + idx + 4);
  bf16x8 o;
  o[0] = (bf16_t)a.x; o[1] = (bf16_t)a.y; o[2] = (bf16_t)a.z; o[3] = (bf16_t)a.w;
  o[4] = (bf16_t)c.x; o[5] = (bf16_t)c.y; o[6] = (bf16_t)c.z; o[7] = (bf16_t)c.w;
  *(bf16x8*)(dst + idx) = o;
}

// ---------------- GEMM: C[M,N] = A[M,K] * B[N,K]^T + bias ----------------
template<bool OUT_BF16>
__global__ __launch_bounds__(256, 2) void gemm_nt(const bf16_t* __restrict__ A,
                                                  const bf16_t* __restrict__ B,
                                                  const float* __restrict__ bias,
                                                  void* __restrict__ Cout,
                                                  int M, int N, int K) {
  __shared__ __align__(16) bf16_t As[128 * 64];
  __shared__ __align__(16) bf16_t Bs[128 * 64];
  const int t = threadIdx.x;
  const int lane = t & 63, wave = t >> 6;
  const int quad = lane >> 4, l15 = lane & 15;
  const int wy = wave >> 1, wx = wave & 1;
  const size_t bm = (size_t)blockIdx.y * 128, bn = (size_t)blockIdx.x * 128;
  const bf16_t* Ab = A + bm * K;
  const bf16_t* Bb = B + bn * K;
  f32x4 acc[4][4] = {};
  int srow[4], scol[4];
#pragma unroll
  for (int r = 0; r < 4; r++) {
    int L = r * 256 + t;
    int row = L >> 3, cp = L & 7;
    srow[r] = row;
    scol[r] = (cp ^ (row & 7)) * 8;
  }
  for (int k0 = 0; k0 < K; k0 += 64) {
    __syncthreads();
#pragma unroll
    for (int r = 0; r < 4; r++)
      async16(Ab + (size_t)srow[r] * K + k0 + scol[r], &As[(r * 256 + t) * 8]);
#pragma unroll
    for (int r = 0; r < 4; r++)
      async16(Bb + (size_t)srow[r] * K + k0 + scol[r], &Bs[(r * 256 + t) * 8]);
    __syncthreads();
#pragma unroll
    for (int ks = 0; ks < 2; ks++) {
      bf16x8 af[4], bfv[4];
#pragma unroll
      for (int i = 0; i < 4; i++) {
        int row = wy * 64 + i * 16 + l15;
        af[i] = *(const bf16x8*)&As[row * 64 + (((ks * 4 + quad) ^ (row & 7)) * 8)];
      }
#pragma unroll
      for (int j = 0; j < 4; j++) {
        int row = wx * 64 + j * 16 + l15;
        bfv[j] = *(const bf16x8*)&Bs[row * 64 + (((ks * 4 + quad) ^ (row & 7)) * 8)];
      }
#pragma unroll
      for (int i = 0; i < 4; i++)
#pragma unroll
        for (int j = 0; j < 4; j++)
          acc[i][j] = __builtin_amdgcn_mfma_f32_16x16x32_bf16(af[i], bfv[j], acc[i][j], 0, 0, 0);
    }
  }
#pragma unroll
  for (int i = 0; i < 4; i++) {
#pragma unroll
    for (int j = 0; j < 4; j++) {
      size_t row = bm + wy * 64 + i * 16 + quad * 4;
      size_t col = bn + wx * 64 + j * 16 + l15;
      float bb = bias[col];
#pragma unroll
      for (int r = 0; r < 4; r++) {
        float v = acc[i][j][r] + bb;
        if (OUT_BF16) ((bf16_t*)Cout)[(row + r) * N + col] = (bf16_t)v;
        else          ((float*)Cout)[(row + r) * N + col] = v;
      }
    }
  }
}

// ---------------- RMS + RoPE; q scaled by 1/sqrt(d)*log2e, k packed to pk ----------------
__global__ __launch_bounds__(256) void rmsrope(bf16_t* __restrict__ qkv,
                                               bf16_t* __restrict__ pk,
                                               const float* __restrict__ gq,
                                               const float* __restrict__ gk,
                                               const float* __restrict__ freqs) {
  const int s = blockIdx.x, t = threadIdx.x;
  // fold softmax scale and exp2-domain conversion into Q
  const float SC2 = 0.08838834764831845f * 1.44269504088896f;
  bf16_t* row = qkv + (size_t)s * QKVN;
  bf16x8 qv = *(const bf16x8*)&row[t * 8];
  bf16x8 kv = *(const bf16x8*)&row[2048 + t * 8];
  float qf[8], kf[8];
  float qs = 0.f, ks2 = 0.f;
#pragma unroll
  for (int i = 0; i < 8; i++) {
    qf[i] = (float)qv[i]; qs  += qf[i] * qf[i];
    kf[i] = (float)kv[i]; ks2 += kf[i] * kf[i];
  }
#pragma unroll
  for (int m = 1; m < 64; m <<= 1) {
    qs  += __shfl_xor(qs, m);
    ks2 += __shfl_xor(ks2, m);
  }
  __shared__ float red[2][4];
  const int wave = t >> 6, lane = t & 63;
  if (lane == 0) { red[0][wave] = qs; red[1][wave] = ks2; }
  __syncthreads();
  qs  = red[0][0] + red[0][1] + red[0][2] + red[0][3];
  ks2 = red[1][0] + red[1][1] + red[1][2] + red[1][3];
  const float qsc = rsqrtf(qs  / 2048.f + 1e-6f) * SC2;
  const float ksc = rsqrtf(ks2 / 2048.f + 1e-6f);
  const int sf = s / 384, rem = s - sf * 384;
  const int sh = rem / 24, sw = rem - sh * 24;
  bf16x8 qo, ko;
#pragma unroll
  for (int u = 0; u < 4; u++) {
    const int col = t * 8 + 2 * u;
    const int i = (col >> 1) & 63;                         // pair index within head (c=64)
    const int frow = (i < 22) ? sf : ((i < 43) ? sh : sw); // cf=22, ch=cw=21
    const float ang = freqs[frow * 64 + i];
    float sn, cs;
    __sincosf(ang, &sn, &cs);
    float te = qf[2 * u]     * qsc * gq[col];
    float to = qf[2 * u + 1] * qsc * gq[col + 1];
    qo[2 * u]     = (bf16_t)(te * cs - to * sn);
    qo[2 * u + 1] = (bf16_t)(te * sn + to * cs);
    te = kf[2 * u]     * ksc * gk[col];
    to = kf[2 * u + 1] * ksc * gk[col + 1];
    ko[2 * u]     = (bf16_t)(te * cs - to * sn);
    ko[2 * u + 1] = (bf16_t)(te * sn + to * cs);
  }
  *(bf16x8*)&row[t * 8] = qo;
  // packed K: pk[h][s][d], h = t>>4, d = (t&15)*8
  *(bf16x8*)&pk[((size_t)(t >> 4) * SEQ + s) * HD + (t & 15) * 8] = ko;
}

// ---------------- V transpose: pvt[h][d][s] = qkv[s][4096 + h*128 + d] ----------------
__global__ __launch_bounds__(256) void vtrans(const bf16_t* __restrict__ qkv,
                                              bf16_t* __restrict__ pvt) {
  __shared__ bf16_t tile[128][65];
  const int h = blockIdx.y;
  const int s0 = blockIdx.x * 64;
  const int t = threadIdx.x;
#pragma unroll
  for (int r = 0; r < 4; r++) {
    int L = r * 256 + t, s = L >> 4, cp = L & 15;
    bf16x8 v = *(const bf16x8*)&qkv[(size_t)(s0 + s) * QKVN + 4096 + h * HD + cp * 8];
#pragma unroll
    for (int i = 0; i < 8; i++) tile[cp * 8 + i][s] = v[i];
  }
  __syncthreads();
#pragma unroll
  for (int r = 0; r < 4; r++) {
    int L = r * 256 + t, d = L >> 3, c = L & 7;
    bf16x8 o;
#pragma unroll
    for (int i = 0; i < 8; i++) o[i] = tile[d][c * 8 + i];
    *(bf16x8*)&pvt[((size_t)h * HD + d) * SEQ + s0 + c * 8] = o;
  }
}

// ---------------- Flash attention: R5 grid + dbuf staging + lean softmax ----------------
// Block = (q-tile 128, head), grid dim3(24,16), 4 waves x 32 q rows.
// Q pre-scaled (exp2 domain). Softmax denominator accumulated via ones-MFMA
// (lacc in C-layout: q = quad*4+r, matching oacc rows -> shuffle-free epilogue).
// Ballot-skipped O/l rescale when all alphas == 1.
__global__ __launch_bounds__(256, 2) void flash_attn(const bf16_t* __restrict__ qkv,
                                                     const bf16_t* __restrict__ pk,
                                                     const bf16_t* __restrict__ pvt,
                                                     bf16_t* __restrict__ ob) {
  __shared__ __align__(16) bf16_t Ks[2][64 * 128];  // [kv][d], 16 chunks/row, xor-swizzled
  __shared__ __align__(16) bf16_t Vt[2][128 * 64];  // [d][kv], 8 chunks/row, xor-swizzled
  __shared__ __align__(16) bf16_t Ps[4][32 * 64];   // per-wave P [q][kv], swizzled
  const int h = blockIdx.y, qt = blockIdx.x;
  const int s0 = qt * 128;
  const int t = threadIdx.x, wave = t >> 6, lane = t & 63;
  const int quad = lane >> 4, l15 = lane & 15;
  const int wq = wave * 32;
  const bf16_t* pkh = pk  + (size_t)h * (SEQ * HD);
  const bf16_t* pvh = pvt + (size_t)h * (HD * SEQ);
  // staging index precompute (per thread: 4 K-chunks + 4 V-chunks)
  int krow4[4], kc4[4], vd4[4], vc4[4];
#pragma unroll
  for (int r = 0; r < 4; r++) {
    int L = r * 256 + t;
    krow4[r] = L >> 4; kc4[r] = (L & 15) ^ (krow4[r] & 7);
    vd4[r]   = L >> 3; vc4[r] = (L & 7)  ^ (vd4[r] & 7);
  }
  bf16x8 qfr[2][4];
#pragma unroll
  for (int tj = 0; tj < 2; tj++)
#pragma unroll
    for (int ks = 0; ks < 4; ks++)
      qfr[tj][ks] = *(const bf16x8*)&qkv[(size_t)(s0 + wq + tj * 16 + l15) * QKVN + h * HD + ks * 32 + quad * 8];
  bf16x8 onesf;
#pragma unroll
  for (int i = 0; i < 8; i++) onesf[i] = (bf16_t)1.0f;
  f32x4 oacc[2][8] = {};
  f32x4 lacc[2] = {};
  float m_run[2] = {-3e38f, -3e38f};
  // preload tile 0 into buffer 0
#pragma unroll
  for (int r = 0; r < 4; r++) {
    int L = r * 256 + t;
    async16(pkh + (size_t)krow4[r] * HD + kc4[r] * 8, &Ks[0][L * 8]);
  }
#pragma unroll
  for (int r = 0; r < 4; r++) {
    int L = r * 256 + t;
    async16(pvh + (size_t)vd4[r] * SEQ + vc4[r] * 8, &Vt[0][L * 8]);
  }
  for (int kt = 0; kt < SEQ / 64; kt++) {
    const int cur = kt & 1;
    __syncthreads();  // tile kt landed; all waves done reading buf cur^1
    if (kt + 1 < SEQ / 64) {
      const int kv1 = (kt + 1) * 64;
#pragma unroll
      for (int r = 0; r < 4; r++) {
        int L = r * 256 + t;
        async16(pkh + (size_t)(kv1 + krow4[r]) * HD + kc4[r] * 8, &Ks[cur ^ 1][L * 8]);
      }
#pragma unroll
      for (int r = 0; r < 4; r++) {
        int L = r * 256 + t;
        async16(pvh + (size_t)vd4[r] * SEQ + kv1 + vc4[r] * 8, &Vt[cur ^ 1][L * 8]);
      }
    }
    // S^T = K * Q^T  -> lane holds S^T[kv=ti*16+quad*4+r][q=tj*16+l15], exp2 domain
    f32x4 st[4][2] = {};
#pragma unroll
    for (int ks = 0; ks < 4; ks++) {
      bf16x8 kfr[4];
#pragma unroll
      for (int ti = 0; ti < 4; ti++) {
        const int kr = ti * 16 + l15;
        kfr[ti] = *(const bf16x8*)&Ks[cur][kr * 128 + (((ks * 4 + quad) ^ (kr & 7)) * 8)];
      }
#pragma unroll
      for (int ti = 0; ti < 4; ti++)
#pragma unroll
        for (int tj = 0; tj < 2; tj++)
          st[ti][tj] = __builtin_amdgcn_mfma_f32_16x16x32_bf16(kfr[ti], qfr[tj][ks], st[ti][tj], 0, 0, 0);
    }
    // online softmax over kv (column reduction of S^T = across quads)
    float mt[2] = {-3e38f, -3e38f};
#pragma unroll
    for (int ti = 0; ti < 4; ti++)
#pragma unroll
      for (int tj = 0; tj < 2; tj++)
#pragma unroll
        for (int r = 0; r < 4; r++)
          mt[tj] = fmaxf(mt[tj], st[ti][tj][r]);
    float al[2];
#pragma unroll
    for (int tj = 0; tj < 2; tj++) {
      mt[tj] = fmaxf(mt[tj], __shfl_xor(mt[tj], 16));
      mt[tj] = fmaxf(mt[tj], __shfl_xor(mt[tj], 32));
      const float mn = fmaxf(m_run[tj], mt[tj]);
      al[tj] = exp2f(m_run[tj] - mn);
      m_run[tj] = mn;
    }
#pragma unroll
    for (int ti = 0; ti < 4; ti++)
#pragma unroll
      for (int tj = 0; tj < 2; tj++) {
        bf16x4 pv;
#pragma unroll
        for (int r = 0; r < 4; r++)
          pv[r] = (bf16_t)exp2f(st[ti][tj][r] - m_run[tj]);
        const int q = tj * 16 + l15;
        const int cp2 = (ti * 2 + (quad >> 1)) ^ (q & 7);
        *(bf16x4*)&Ps[wave][q * 64 + cp2 * 8 + (quad & 1) * 4] = pv;
      }
    // rescale O and l accumulators only when some alpha != 1 (exact skip)
    if (__ballot((al[0] != 1.f) | (al[1] != 1.f))) {
#pragma unroll
      for (int ti = 0; ti < 2; ti++) {
        float a0 = __shfl(al[ti], quad * 4 + 0);
        float a1 = __shfl(al[ti], quad * 4 + 1);
        float a2 = __shfl(al[ti], quad * 4 + 2);
        float a3 = __shfl(al[ti], quad * 4 + 3);
        lacc[ti][0] *= a0; lacc[ti][1] *= a1;
        lacc[ti][2] *= a2; lacc[ti][3] *= a3;
#pragma unroll
        for (int dj = 0; dj < 8; dj++) {
          oacc[ti][dj][0] *= a0; oacc[ti][dj][1] *= a1;
          oacc[ti][dj][2] *= a2; oacc[ti][dj][3] *= a3;
        }
      }
    }
    // O += P * V ;  l += P * 1 (ones-MFMA, C-layout rows q=quad*4+r)
#pragma unroll
    for (int ks = 0; ks < 2; ks++) {
      bf16x8 pf[2], vf[8];
#pragma unroll
      for (int ti = 0; ti < 2; ti++) {
        const int q = ti * 16 + l15;
        pf[ti] = *(const bf16x8*)&Ps[wave][q * 64 + (((ks * 4 + quad) ^ (q & 7)) * 8)];
      }
#pragma unroll
      for (int dj = 0; dj < 8; dj++) {
        const int d = dj * 16 + l15;
        vf[dj] = *(const bf16x8*)&Vt[cur][d * 64 + (((ks * 4 + quad) ^ (d & 7)) * 8)];
      }
#pragma unroll
      for (int ti = 0; ti < 2; ti++) {
        lacc[ti] = __builtin_amdgcn_mfma_f32_16x16x32_bf16(pf[ti], onesf, lacc[ti], 0, 0, 0);
#pragma unroll
        for (int dj = 0; dj < 8; dj++)
          oacc[ti][dj] = __builtin_amdgcn_mfma_f32_16x16x32_bf16(pf[ti], vf[dj], oacc[ti][dj], 0, 0, 0);
      }
    }
  }
  // epilogue: divide by l (shuffle-free: lacc rows already q=quad*4+r), store bf16
#pragma unroll
  for (int ti = 0; ti < 2; ti++) {
    float li[4];
#pragma unroll
    for (int r = 0; r < 4; r++) li[r] = 1.f / lacc[ti][r];
#pragma unroll
    for (int dj = 0; dj < 8; dj++)
#pragma unroll
      for (int r = 0; r < 4; r++) {
        const float v = oacc[ti][dj][r] * li[r];
        ob[(size_t)(s0 + wq + ti * 16 + quad * 4 + r) * DIMD + h * HD + dj * 16 + l15] = (bf16_t)v;
      }
  }
}

// ---------------- launch ----------------
extern "C" void kernel_launch(void* const* d_in, const int* in_sizes, int n_in,
                              void* d_out, int out_size, void* d_ws, size_t ws_size,
                              hipStream_t stream) {
  (void)in_sizes; (void)n_in; (void)out_size;
  const float* x     = (const float*)d_in[0];
  const float* freqs = (const float*)d_in[1];
  const float* Wq    = (const float*)d_in[2];
  const float* bq    = (const float*)d_in[3];
  const float* Wk    = (const float*)d_in[4];
  const float* bk    = (const float*)d_in[5];
  const float* Wv    = (const float*)d_in[6];
  const float* bv    = (const float*)d_in[7];
  const float* Wo    = (const float*)d_in[8];
  const float* bo    = (const float*)d_in[9];
  const float* gq    = (const float*)d_in[10];
  const float* gk    = (const float*)d_in[11];

  // workspace carve (bytes); [0, 37748736) holds xb+Wqkvb during gemm1,
  // reused afterwards for pk / pvt.
  char* w = (char*)d_ws;
  bf16_t* xb    = (bf16_t*)(w);                 // x bf16:        12,582,912 B
  bf16_t* Wqkvb = (bf16_t*)(w + 12582912);      // Wq|Wk|Wv bf16: 25,165,824 B
  bf16_t* Wob   = (bf16_t*)(w + 37748736);      // Wo bf16:        8,388,608 B
  bf16_t* qkvb  = (bf16_t*)(w + 46137344);      // qkv bf16:      37,748,736 B
  bf16_t* obuf  = (bf16_t*)(w + 83886080);      // attn out bf16: 12,582,912 B
  float*  bqkv  = (float*) (w + 96468992);      // stacked bias:      24,576 B
  bf16_t* pk    = (bf16_t*)(w);                 // K packed [16][3072][128]: 12,582,912 B
  bf16_t* pvt   = (bf16_t*)(w + 12582912);      // V^T [16][128][3072]:      12,582,912 B
  if (ws_size < (size_t)96493568) return;

  // converts + bias pack (one launch)
  cvt_all<<<11288, 256, 0, stream>>>(x, Wq, Wk, Wv, Wo, bq, bk, bv, xb, Wqkvb, Wob, bqkv);

  // qkv = x @ [Wq;Wk;Wv]^T + bias   (3072 x 6144 x 2048)
  gemm_nt<true><<<dim3(48, 24), 256, 0, stream>>>(xb, Wqkvb, bqkv, qkvb, SEQ, QKVN, DIMD);
  // RMS(q,k) * g + grid RoPE; q (pre-scaled) in-place, k -> pk (packed per head)
  rmsrope<<<3072, 256, 0, stream>>>(qkvb, pk, gq, gk, freqs);
  // V transpose -> pvt[h][d][s]
  vtrans<<<dim3(48, NH), 256, 0, stream>>>(qkvb, pvt);
  // attention (R5 grid, double-buffered, lean softmax) -> obuf
  flash_attn<<<dim3(24, NH), 256, 0, stream>>>(qkvb, pk, pvt, obuf);
  // out = obuf @ Wo^T + bo  (3072 x 2048 x 2048), fp32 out
  gemm_nt<false><<<dim3(16, 24), 256, 0, stream>>>(obuf, Wob, bo, (float*)d_out, SEQ, DIMD, DIMD);
}

// Round 8
// 438.445 us; speedup vs baseline: 1.0638x; 1.0174x over previous
//
#include <hip/hip_runtime.h>
#include <stdint.h>
#include <stddef.h>

typedef __bf16 bf16_t;
typedef __bf16 bf16x8 __attribute__((ext_vector_type(8)));
typedef __bf16 bf16x4 __attribute__((ext_vector_type(4)));
typedef __bf16 bf16x2 __attribute__((ext_vector_type(2)));
typedef float  f32x4  __attribute__((ext_vector_type(4)));

#define SEQ   3072
#define DIMD  2048
#define NH    16
#define HD    128
#define QKVN  6144

__device__ __forceinline__ void async16(const bf16_t* g, bf16_t* l) {
  __builtin_amdgcn_global_load_lds((const __attribute__((address_space(1))) uint32_t*)g,
                                   (__attribute__((address_space(3))) uint32_t*)l, 16, 0, 0);
}

// ---------------- fused converts + bias pack (one launch) ----------------
__global__ __launch_bounds__(256) void cvt_all(const float* __restrict__ x,
                                               const float* __restrict__ Wq,
                                               const float* __restrict__ Wk,
                                               const float* __restrict__ Wv,
                                               const float* __restrict__ Wo,
                                               const float* __restrict__ bq,
                                               const float* __restrict__ bk,
                                               const float* __restrict__ bv,
                                               bf16_t* __restrict__ xb,
                                               bf16_t* __restrict__ Wqkvb,
                                               bf16_t* __restrict__ Wob,
                                               float* __restrict__ bqkv) {
  const int b = blockIdx.x;
  const float* src; bf16_t* dst; int off;
  if (b < 3072)       { src = x;  dst = xb;              off = b; }
  else if (b < 5120)  { src = Wq; dst = Wqkvb;           off = b - 3072; }
  else if (b < 7168)  { src = Wk; dst = Wqkvb + 4194304; off = b - 5120; }
  else if (b < 9216)  { src = Wv; dst = Wqkvb + 8388608; off = b - 7168; }
  else if (b < 11264) { src = Wo; dst = Wob;             off = b - 9216; }
  else {  // bias pack: 24 blocks cover 6144
    int t = (b - 11264) * 256 + threadIdx.x;
    float v;
    if (t < 2048)      v = bq[t];
    else if (t < 4096) v = bk[t - 2048];
    else               v = bv[t - 4096];
    bqkv[t] = v;
    return;
  }
  const int idx = (off * 256 + threadIdx.x) * 8;
  const float4 a = *(const float4*)(src + idx);
  const float4 c = *(const float4*)(src + idx + 4);
  bf16x8 o;
  o[0] = (bf16_t)a.x; o[1] = (bf16_t)a.y; o[2] = (bf16_t)a.z; o[3] = (bf16_t)a.w;
  o[4] = (bf16_t)c.x; o[5] = (bf16_t)c.y; o[6] = (bf16_t)c.z; o[7] = (bf16_t)c.w;
  *(bf16x8*)(dst + idx) = o;
}

// ---------------- GEMM: C[M,N] = A[M,K] * B[N,K]^T + bias ----------------
// 128x128 tile, BK=64, 4 waves of 64x64. launch_bounds(256,3): cap arch VGPRs
// at ~170 -> 3 waves/SIMD (m97-proven budget for this exact structure).
template<bool OUT_BF16>
__global__ __launch_bounds__(256, 3) void gemm_nt(const bf16_t* __restrict__ A,
                                                  const bf16_t* __restrict__ B,
                                                  const float* __restrict__ bias,
                                                  void* __restrict__ Cout,
                                                  int M, int N, int K) {
  __shared__ __align__(16) bf16_t As[128 * 64];
  __shared__ __align__(16) bf16_t Bs[128 * 64];
  const int t = threadIdx.x;
  const int lane = t & 63, wave = t >> 6;
  const int quad = lane >> 4, l15 = lane & 15;
  const int wy = wave >> 1, wx = wave & 1;
  const size_t bm = (size_t)blockIdx.y * 128, bn = (size_t)blockIdx.x * 128;
  const bf16_t* Ab = A + bm * K;
  const bf16_t* Bb = B + bn * K;
  f32x4 acc[4][4] = {};
  int srow[4], scol[4];
#pragma unroll
  for (int r = 0; r < 4; r++) {
    int L = r * 256 + t;
    int row = L >> 3, cp = L & 7;
    srow[r] = row;
    scol[r] = (cp ^ (row & 7)) * 8;
  }
  for (int k0 = 0; k0 < K; k0 += 64) {
    __syncthreads();
#pragma unroll
    for (int r = 0; r < 4; r++)
      async16(Ab + (size_t)srow[r] * K + k0 + scol[r], &As[(r * 256 + t) * 8]);
#pragma unroll
    for (int r = 0; r < 4; r++)
      async16(Bb + (size_t)srow[r] * K + k0 + scol[r], &Bs[(r * 256 + t) * 8]);
    __syncthreads();
#pragma unroll
    for (int ks = 0; ks < 2; ks++) {
      bf16x8 af[4], bfv[4];
#pragma unroll
      for (int i = 0; i < 4; i++) {
        int row = wy * 64 + i * 16 + l15;
        af[i] = *(const bf16x8*)&As[row * 64 + (((ks * 4 + quad) ^ (row & 7)) * 8)];
      }
#pragma unroll
      for (int j = 0; j < 4; j++) {
        int row = wx * 64 + j * 16 + l15;
        bfv[j] = *(const bf16x8*)&Bs[row * 64 + (((ks * 4 + quad) ^ (row & 7)) * 8)];
      }
#pragma unroll
      for (int i = 0; i < 4; i++)
#pragma unroll
        for (int j = 0; j < 4; j++)
          acc[i][j] = __builtin_amdgcn_mfma_f32_16x16x32_bf16(af[i], bfv[j], acc[i][j], 0, 0, 0);
    }
  }
#pragma unroll
  for (int i = 0; i < 4; i++) {
#pragma unroll
    for (int j = 0; j < 4; j++) {
      size_t row = bm + wy * 64 + i * 16 + quad * 4;
      size_t col = bn + wx * 64 + j * 16 + l15;
      float bb = bias[col];
#pragma unroll
      for (int r = 0; r < 4; r++) {
        float v = acc[i][j][r] + bb;
        if (OUT_BF16) ((bf16_t*)Cout)[(row + r) * N + col] = (bf16_t)v;
        else          ((float*)Cout)[(row + r) * N + col] = v;
      }
    }
  }
}

// ---------------- GEMM variant: 128x64 tile (for N=2048 -> 768 blocks = 3/CU) ----------
// 4 waves of 64x32. LDS 24 KB; acc 8 f32x4 -> low reg pressure, 3 blocks/CU balanced.
template<bool OUT_BF16>
__global__ __launch_bounds__(256, 3) void gemm_nt64(const bf16_t* __restrict__ A,
                                                    const bf16_t* __restrict__ B,
                                                    const float* __restrict__ bias,
                                                    void* __restrict__ Cout,
                                                    int M, int N, int K) {
  __shared__ __align__(16) bf16_t As[128 * 64];  // 16 KB
  __shared__ __align__(16) bf16_t Bs[64 * 64];   //  8 KB
  const int t = threadIdx.x;
  const int lane = t & 63, wave = t >> 6;
  const int quad = lane >> 4, l15 = lane & 15;
  const int wy = wave >> 1, wx = wave & 1;
  const size_t bm = (size_t)blockIdx.y * 128, bn = (size_t)blockIdx.x * 64;
  const bf16_t* Ab = A + bm * K;
  const bf16_t* Bb = B + bn * K;
  f32x4 acc[4][2] = {};
  for (int k0 = 0; k0 < K; k0 += 64) {
    __syncthreads();
#pragma unroll
    for (int r = 0; r < 4; r++) {
      int L = r * 256 + t, row = L >> 3, cp = L & 7;
      async16(Ab + (size_t)row * K + k0 + (cp ^ (row & 7)) * 8, &As[L * 8]);
    }
#pragma unroll
    for (int r = 0; r < 2; r++) {
      int L = r * 256 + t, row = L >> 3, cp = L & 7;
      async16(Bb + (size_t)row * K + k0 + (cp ^ (row & 7)) * 8, &Bs[L * 8]);
    }
    __syncthreads();
#pragma unroll
    for (int ks = 0; ks < 2; ks++) {
      bf16x8 af[4], bfv[2];
#pragma unroll
      for (int i = 0; i < 4; i++) {
        int row = wy * 64 + i * 16 + l15;
        af[i] = *(const bf16x8*)&As[row * 64 + (((ks * 4 + quad) ^ (row & 7)) * 8)];
      }
#pragma unroll
      for (int j = 0; j < 2; j++) {
        int row = wx * 32 + j * 16 + l15;
        bfv[j] = *(const bf16x8*)&Bs[row * 64 + (((ks * 4 + quad) ^ (row & 7)) * 8)];
      }
#pragma unroll
      for (int i = 0; i < 4; i++)
#pragma unroll
        for (int j = 0; j < 2; j++)
          acc[i][j] = __builtin_amdgcn_mfma_f32_16x16x32_bf16(af[i], bfv[j], acc[i][j], 0, 0, 0);
    }
  }
#pragma unroll
  for (int i = 0; i < 4; i++) {
#pragma unroll
    for (int j = 0; j < 2; j++) {
      size_t row = bm + wy * 64 + i * 16 + quad * 4;
      size_t col = bn + wx * 32 + j * 16 + l15;
      float bb = bias[col];
#pragma unroll
      for (int r = 0; r < 4; r++) {
        float v = acc[i][j][r] + bb;
        if (OUT_BF16) ((bf16_t*)Cout)[(row + r) * N + col] = (bf16_t)v;
        else          ((float*)Cout)[(row + r) * N + col] = v;
      }
    }
  }
}

// ---------------- RMS + RoPE; q scaled by 1/sqrt(d)*log2e, k packed to pk ----------------
__global__ __launch_bounds__(256) void rmsrope(bf16_t* __restrict__ qkv,
                                               bf16_t* __restrict__ pk,
                                               const float* __restrict__ gq,
                                               const float* __restrict__ gk,
                                               const float* __restrict__ freqs) {
  const int s = blockIdx.x, t = threadIdx.x;
  // fold softmax scale and exp2-domain conversion into Q
  const float SC2 = 0.08838834764831845f * 1.44269504088896f;
  bf16_t* row = qkv + (size_t)s * QKVN;
  bf16x8 qv = *(const bf16x8*)&row[t * 8];
  bf16x8 kv = *(const bf16x8*)&row[2048 + t * 8];
  float qf[8], kf[8];
  float qs = 0.f, ks2 = 0.f;
#pragma unroll
  for (int i = 0; i < 8; i++) {
    qf[i] = (float)qv[i]; qs  += qf[i] * qf[i];
    kf[i] = (float)kv[i]; ks2 += kf[i] * kf[i];
  }
#pragma unroll
  for (int m = 1; m < 64; m <<= 1) {
    qs  += __shfl_xor(qs, m);
    ks2 += __shfl_xor(ks2, m);
  }
  __shared__ float red[2][4];
  const int wave = t >> 6, lane = t & 63;
  if (lane == 0) { red[0][wave] = qs; red[1][wave] = ks2; }
  __syncthreads();
  qs  = red[0][0] + red[0][1] + red[0][2] + red[0][3];
  ks2 = red[1][0] + red[1][1] + red[1][2] + red[1][3];
  const float qsc = rsqrtf(qs  / 2048.f + 1e-6f) * SC2;
  const float ksc = rsqrtf(ks2 / 2048.f + 1e-6f);
  const int sf = s / 384, rem = s - sf * 384;
  const int sh = rem / 24, sw = rem - sh * 24;
  bf16x8 qo, ko;
#pragma unroll
  for (int u = 0; u < 4; u++) {
    const int col = t * 8 + 2 * u;
    const int i = (col >> 1) & 63;                         // pair index within head (c=64)
    const int frow = (i < 22) ? sf : ((i < 43) ? sh : sw); // cf=22, ch=cw=21
    const float ang = freqs[frow * 64 + i];
    float sn, cs;
    __sincosf(ang, &sn, &cs);
    float te = qf[2 * u]     * qsc * gq[col];
    float to = qf[2 * u + 1] * qsc * gq[col + 1];
    qo[2 * u]     = (bf16_t)(te * cs - to * sn);
    qo[2 * u + 1] = (bf16_t)(te * sn + to * cs);
    te = kf[2 * u]     * ksc * gk[col];
    to = kf[2 * u + 1] * ksc * gk[col + 1];
    ko[2 * u]     = (bf16_t)(te * cs - to * sn);
    ko[2 * u + 1] = (bf16_t)(te * sn + to * cs);
  }
  *(bf16x8*)&row[t * 8] = qo;
  // packed K: pk[h][s][d], h = t>>4, d = (t&15)*8
  *(bf16x8*)&pk[((size_t)(t >> 4) * SEQ + s) * HD + (t & 15) * 8] = ko;
}

// ---------------- V transpose: pvt[h][d][s] = qkv[s][4096 + h*128 + d] ----------------
__global__ __launch_bounds__(256) void vtrans(const bf16_t* __restrict__ qkv,
                                              bf16_t* __restrict__ pvt) {
  __shared__ bf16_t tile[128][65];
  const int h = blockIdx.y;
  const int s0 = blockIdx.x * 64;
  const int t = threadIdx.x;
#pragma unroll
  for (int r = 0; r < 4; r++) {
    int L = r * 256 + t, s = L >> 4, cp = L & 15;
    bf16x8 v = *(const bf16x8*)&qkv[(size_t)(s0 + s) * QKVN + 4096 + h * HD + cp * 8];
#pragma unroll
    for (int i = 0; i < 8; i++) tile[cp * 8 + i][s] = v[i];
  }
  __syncthreads();
#pragma unroll
  for (int r = 0; r < 4; r++) {
    int L = r * 256 + t, d = L >> 3, c = L & 7;
    bf16x8 o;
#pragma unroll
    for (int i = 0; i < 8; i++) o[i] = tile[d][c * 8 + i];
    *(bf16x8*)&pvt[((size_t)h * HD + d) * SEQ + s0 + c * 8] = o;
  }
}

// ---------------- Flash attention: R5 grid + dbuf staging + lean softmax ----------------
// Block = (q-tile 128, head), grid dim3(24,16), 4 waves x 32 q rows.
// Q pre-scaled (exp2 domain). Softmax denominator accumulated via ones-MFMA
// (lacc in C-layout: q = quad*4+r, matching oacc rows -> shuffle-free epilogue).
// Ballot-skipped O/l rescale when all alphas == 1.
__global__ __launch_bounds__(256, 2) void flash_attn(const bf16_t* __restrict__ qkv,
                                                     const bf16_t* __restrict__ pk,
                                                     const bf16_t* __restrict__ pvt,
                                                     bf16_t* __restrict__ ob) {
  __shared__ __align__(16) bf16_t Ks[2][64 * 128];  // [kv][d], 16 chunks/row, xor-swizzled
  __shared__ __align__(16) bf16_t Vt[2][128 * 64];  // [d][kv], 8 chunks/row, xor-swizzled
  __shared__ __align__(16) bf16_t Ps[4][32 * 64];   // per-wave P [q][kv], swizzled
  const int h = blockIdx.y, qt = blockIdx.x;
  const int s0 = qt * 128;
  const int t = threadIdx.x, wave = t >> 6, lane = t & 63;
  const int quad = lane >> 4, l15 = lane & 15;
  const int wq = wave * 32;
  const bf16_t* pkh = pk  + (size_t)h * (SEQ * HD);
  const bf16_t* pvh = pvt + (size_t)h * (HD * SEQ);
  // staging index precompute (per thread: 4 K-chunks + 4 V-chunks)
  int krow4[4], kc4[4], vd4[4], vc4[4];
#pragma unroll
  for (int r = 0; r < 4; r++) {
    int L = r * 256 + t;
    krow4[r] = L >> 4; kc4[r] = (L & 15) ^ (krow4[r] & 7);
    vd4[r]   = L >> 3; vc4[r] = (L & 7)  ^ (vd4[r] & 7);
  }
  bf16x8 qfr[2][4];
#pragma unroll
  for (int tj = 0; tj < 2; tj++)
#pragma unroll
    for (int ks = 0; ks < 4; ks++)
      qfr[tj][ks] = *(const bf16x8*)&qkv[(size_t)(s0 + wq + tj * 16 + l15) * QKVN + h * HD + ks * 32 + quad * 8];
  bf16x8 onesf;
#pragma unroll
  for (int i = 0; i < 8; i++) onesf[i] = (bf16_t)1.0f;
  f32x4 oacc[2][8] = {};
  f32x4 lacc[2] = {};
  float m_run[2] = {-3e38f, -3e38f};
  // preload tile 0 into buffer 0
#pragma unroll
  for (int r = 0; r < 4; r++) {
    int L = r * 256 + t;
    async16(pkh + (size_t)krow4[r] * HD + kc4[r] * 8, &Ks[0][L * 8]);
  }
#pragma unroll
  for (int r = 0; r < 4; r++) {
    int L = r * 256 + t;
    async16(pvh + (size_t)vd4[r] * SEQ + vc4[r] * 8, &Vt[0][L * 8]);
  }
  for (int kt = 0; kt < SEQ / 64; kt++) {
    const int cur = kt & 1;
    __syncthreads();  // tile kt landed; all waves done reading buf cur^1
    if (kt + 1 < SEQ / 64) {
      const int kv1 = (kt + 1) * 64;
#pragma unroll
      for (int r = 0; r < 4; r++) {
        int L = r * 256 + t;
        async16(pkh + (size_t)(kv1 + krow4[r]) * HD + kc4[r] * 8, &Ks[cur ^ 1][L * 8]);
      }
#pragma unroll
      for (int r = 0; r < 4; r++) {
        int L = r * 256 + t;
        async16(pvh + (size_t)vd4[r] * SEQ + kv1 + vc4[r] * 8, &Vt[cur ^ 1][L * 8]);
      }
    }
    // S^T = K * Q^T  -> lane holds S^T[kv=ti*16+quad*4+r][q=tj*16+l15], exp2 domain
    f32x4 st[4][2] = {};
#pragma unroll
    for (int ks = 0; ks < 4; ks++) {
      bf16x8 kfr[4];
#pragma unroll
      for (int ti = 0; ti < 4; ti++) {
        const int kr = ti * 16 + l15;
        kfr[ti] = *(const bf16x8*)&Ks[cur][kr * 128 + (((ks * 4 + quad) ^ (kr & 7)) * 8)];
      }
#pragma unroll
      for (int ti = 0; ti < 4; ti++)
#pragma unroll
        for (int tj = 0; tj < 2; tj++)
          st[ti][tj] = __builtin_amdgcn_mfma_f32_16x16x32_bf16(kfr[ti], qfr[tj][ks], st[ti][tj], 0, 0, 0);
    }
    // online softmax over kv (column reduction of S^T = across quads)
    float mt[2] = {-3e38f, -3e38f};
#pragma unroll
    for (int ti = 0; ti < 4; ti++)
#pragma unroll
      for (int tj = 0; tj < 2; tj++)
#pragma unroll
        for (int r = 0; r < 4; r++)
          mt[tj] = fmaxf(mt[tj], st[ti][tj][r]);
    float al[2];
#pragma unroll
    for (int tj = 0; tj < 2; tj++) {
      mt[tj] = fmaxf(mt[tj], __shfl_xor(mt[tj], 16));
      mt[tj] = fmaxf(mt[tj], __shfl_xor(mt[tj], 32));
      const float mn = fmaxf(m_run[tj], mt[tj]);
      al[tj] = exp2f(m_run[tj] - mn);
      m_run[tj] = mn;
    }
#pragma unroll
    for (int ti = 0; ti < 4; ti++)
#pragma unroll
      for (int tj = 0; tj < 2; tj++) {
        bf16x4 pv;
#pragma unroll
        for (int r = 0; r < 4; r++)
          pv[r] = (bf16_t)exp2f(st[ti][tj][r] - m_run[tj]);
        const int q = tj * 16 + l15;
        const int cp2 = (ti * 2 + (quad >> 1)) ^ (q & 7);
        *(bf16x4*)&Ps[wave][q * 64 + cp2 * 8 + (quad & 1) * 4] = pv;
      }
    // rescale O and l accumulators only when some alpha != 1 (exact skip)
    if (__ballot((al[0] != 1.f) | (al[1] != 1.f))) {
#pragma unroll
      for (int ti = 0; ti < 2; ti++) {
        float a0 = __shfl(al[ti], quad * 4 + 0);
        float a1 = __shfl(al[ti], quad * 4 + 1);
        float a2 = __shfl(al[ti], quad * 4 + 2);
        float a3 = __shfl(al[ti], quad * 4 + 3);
        lacc[ti][0] *= a0; lacc[ti][1] *= a1;
        lacc[ti][2] *= a2; lacc[ti][3] *= a3;
#pragma unroll
        for (int dj = 0; dj < 8; dj++) {
          oacc[ti][dj][0] *= a0; oacc[ti][dj][1] *= a1;
          oacc[ti][dj][2] *= a2; oacc[ti][dj][3] *= a3;
        }
      }
    }
    // O += P * V ;  l += P * 1 (ones-MFMA, C-layout rows q=quad*4+r)
#pragma unroll
    for (int ks = 0; ks < 2; ks++) {
      bf16x8 pf[2], vf[8];
#pragma unroll
      for (int ti = 0; ti < 2; ti++) {
        const int q = ti * 16 + l15;
        pf[ti] = *(const bf16x8*)&Ps[wave][q * 64 + (((ks * 4 + quad) ^ (q & 7)) * 8)];
      }
#pragma unroll
      for (int dj = 0; dj < 8; dj++) {
        const int d = dj * 16 + l15;
        vf[dj] = *(const bf16x8*)&Vt[cur][d * 64 + (((ks * 4 + quad) ^ (d & 7)) * 8)];
      }
#pragma unroll
      for (int ti = 0; ti < 2; ti++) {
        lacc[ti] = __builtin_amdgcn_mfma_f32_16x16x32_bf16(pf[ti], onesf, lacc[ti], 0, 0, 0);
#pragma unroll
        for (int dj = 0; dj < 8; dj++)
          oacc[ti][dj] = __builtin_amdgcn_mfma_f32_16x16x32_bf16(pf[ti], vf[dj], oacc[ti][dj], 0, 0, 0);
      }
    }
  }
  // epilogue: divide by l (shuffle-free: lacc rows already q=quad*4+r), store bf16
#pragma unroll
  for (int ti = 0; ti < 2; ti++) {
    float li[4];
#pragma unroll
    for (int r = 0; r < 4; r++) li[r] = 1.f / lacc[ti][r];
#pragma unroll
    for (int dj = 0; dj < 8; dj++)
#pragma unroll
      for (int r = 0; r < 4; r++) {
        const float v = oacc[ti][dj][r] * li[r];
        ob[(size_t)(s0 + wq + ti * 16 + quad * 4 + r) * DIMD + h * HD + dj * 16 + l15] = (bf16_t)v;
      }
  }
}

// ---------------- launch ----------------
extern "C" void kernel_launch(void* const* d_in, const int* in_sizes, int n_in,
                              void* d_out, int out_size, void* d_ws, size_t ws_size,
                              hipStream_t stream) {
  (void)in_sizes; (void)n_in; (void)out_size;
  const float* x     = (const float*)d_in[0];
  const float* freqs = (const float*)d_in[1];
  const float* Wq    = (const float*)d_in[2];
  const float* bq    = (const float*)d_in[3];
  const float* Wk    = (const float*)d_in[4];
  const float* bk    = (const float*)d_in[5];
  const float* Wv    = (const float*)d_in[6];
  const float* bv    = (const float*)d_in[7];
  const float* Wo    = (const float*)d_in[8];
  const float* bo    = (const float*)d_in[9];
  const float* gq    = (const float*)d_in[10];
  const float* gk    = (const float*)d_in[11];

  // workspace carve (bytes); [0, 37748736) holds xb+Wqkvb during gemm1,
  // reused afterwards for pk / pvt.
  char* w = (char*)d_ws;
  bf16_t* xb    = (bf16_t*)(w);                 // x bf16:        12,582,912 B
  bf16_t* Wqkvb = (bf16_t*)(w + 12582912);      // Wq|Wk|Wv bf16: 25,165,824 B
  bf16_t* Wob   = (bf16_t*)(w + 37748736);      // Wo bf16:        8,388,608 B
  bf16_t* qkvb  = (bf16_t*)(w + 46137344);      // qkv bf16:      37,748,736 B
  bf16_t* obuf  = (bf16_t*)(w + 83886080);      // attn out bf16: 12,582,912 B
  float*  bqkv  = (float*) (w + 96468992);      // stacked bias:      24,576 B
  bf16_t* pk    = (bf16_t*)(w);                 // K packed [16][3072][128]: 12,582,912 B
  bf16_t* pvt   = (bf16_t*)(w + 12582912);      // V^T [16][128][3072]:      12,582,912 B
  if (ws_size < (size_t)96493568) return;

  // converts + bias pack (one launch)
  cvt_all<<<11288, 256, 0, stream>>>(x, Wq, Wk, Wv, Wo, bq, bk, bv, xb, Wqkvb, Wob, bqkv);

  // qkv = x @ [Wq;Wk;Wv]^T + bias   (3072 x 6144 x 2048)
  gemm_nt<true><<<dim3(48, 24), 256, 0, stream>>>(xb, Wqkvb, bqkv, qkvb, SEQ, QKVN, DIMD);
  // RMS(q,k) * g + grid RoPE; q (pre-scaled) in-place, k -> pk (packed per head)
  rmsrope<<<3072, 256, 0, stream>>>(qkvb, pk, gq, gk, freqs);
  // V transpose -> pvt[h][d][s]
  vtrans<<<dim3(48, NH), 256, 0, stream>>>(qkvb, pvt);
  // attention (R5 grid, double-buffered, lean softmax) -> obuf
  flash_attn<<<dim3(24, NH), 256, 0, stream>>>(qkvb, pk, pvt, obuf);
  // out = obuf @ Wo^T + bo  (3072 x 2048 x 2048), fp32 out; 128x64 tile -> 768 blocks
  gemm_nt64<false><<<dim3(32, 24), 256, 0, stream>>>(obuf, Wob, bo, (float*)d_out, SEQ, DIMD, DIMD);
}